// Round 3
// baseline (469.862 us; speedup 1.0000x reference)
//
#include <hip/hip_runtime.h>
#include <stdint.h>

#define T_STEPS 512
#define CELLS   4096            // 64*64
#define BPB     16              // batches per block
#define THREADS 64

// cell codes: 2 = goal (g==10, priority), 1 = wall (w==1 && !goal), 0 = free
__device__ __forceinline__ uint32_t pack4(float4 w, float4 g) {
    uint32_t b0 = (g.x == 10.0f) ? 2u : ((w.x == 1.0f) ? 1u : 0u);
    uint32_t b1 = (g.y == 10.0f) ? 2u : ((w.y == 1.0f) ? 1u : 0u);
    uint32_t b2 = (g.z == 10.0f) ? 2u : ((w.z == 1.0f) ? 1u : 0u);
    uint32_t b3 = (g.w == 10.0f) ? 2u : ((w.w == 1.0f) ? 1u : 0u);
    return b0 | (b1 << 8) | (b2 << 16) | (b3 << 24);
}

__global__ __launch_bounds__(THREADS) void rollout_kernel(
    const float* __restrict__ s0,
    const int*   __restrict__ act,
    const float* __restrict__ world,
    float* __restrict__ out,
    int B)
{
    __shared__ uint8_t cells[BPB * CELLS];   // 64 KiB static LDS

    const int tid = threadIdx.x;
    const int b0  = blockIdx.x * BPB;

    // ---- Phase 1: stage 16 batches' worlds, packed to bytes, into LDS ----
    for (int bb = 0; bb < BPB; ++bb) {
        const float* wbase = world + (size_t)(b0 + bb) * (2 * CELLS);
        const float* gbase = wbase + CELLS;
        #pragma unroll
        for (int h = 0; h < 4; ++h) {
            const int c0 = h * 1024 + tid * 16;
            float4 w0 = *(const float4*)(wbase + c0);
            float4 w1 = *(const float4*)(wbase + c0 + 4);
            float4 w2 = *(const float4*)(wbase + c0 + 8);
            float4 w3 = *(const float4*)(wbase + c0 + 12);
            float4 g0 = *(const float4*)(gbase + c0);
            float4 g1 = *(const float4*)(gbase + c0 + 4);
            float4 g2 = *(const float4*)(gbase + c0 + 8);
            float4 g3 = *(const float4*)(gbase + c0 + 12);
            uint4 v = make_uint4(pack4(w0, g0), pack4(w1, g1),
                                 pack4(w2, g2), pack4(w3, g3));
            *(uint4*)(&cells[bb * CELLS + c0]) = v;
        }
    }
    __syncthreads();

    // ---- Phase 2: lanes 0..15 each roll out one batch from LDS ----
    if (tid < BPB) {
        const int b = b0 + tid;
        float2 s = *(const float2*)(s0 + 2 * (size_t)b);
        int r = (int)s.x;
        int c = (int)s.y;
        int p = r * 64 + c;                       // flat index, exactly as reference
        const uint8_t* my = cells + tid * CELLS;

        float* s_out = out + (size_t)b * (2 * (T_STEPS + 1));
        float* r_out = out + (size_t)B * (2 * (T_STEPS + 1)) + (size_t)b * (T_STEPS + 1);

        *(float2*)s_out = s;                      // s_full[:,0] = s0
        r_out[0] = 0.0f;                          // r_full[:,0] = 0

        const int4* ap = (const int4*)(act + (size_t)b * T_STEPS);
        int4 cur = ap[0];
        for (int k = 0; k < T_STEPS / 4; ++k) {
            int4 nxt = (k + 1 < T_STEPS / 4) ? ap[k + 1] : cur;  // prefetch actions
            int as4[4] = {cur.x, cur.y, cur.z, cur.w};
            #pragma unroll
            for (int j = 0; j < 4; ++j) {
                const int t = k * 4 + j;
                const int a = as4[j];
                // action deltas: 1 -> r-1, 2 -> r+1, 3 -> c-1, 4 -> c+1, 0 -> stay
                const int dr = (a == 1) ? -1 : ((a == 2) ? 1 : 0);
                const int dc = (a == 3) ? -1 : ((a == 4) ? 1 : 0);
                const int p1 = p + dr * 64 + dc;          // == r1*64 + c1 exactly
                // jnp.take_along_axis semantics: negative indices normalized
                // once (idx += 4096, NumPy-style), THEN mode='fill' (NaN) for
                // anything still out of [0,4096) -> NaN==10 false, NaN==1
                // false -> free move, reward -0.01.
                const int idxn = p1 + ((p1 < 0) ? CELLS : 0);
                const int cell = ((unsigned)idxn < (unsigned)CELLS) ? my[idxn] : 0;
                const bool hw = (cell == 1);              // wall & !goal
                const float rew = (cell == 2) ? 1.0f : (hw ? -1.0f : -0.01f);
                const int r1 = r + dr, c1 = c + dc;
                if (!hw) { r = r1; c = c1; p = p1; }      // revert on wall hit
                float2 sv = make_float2((float)r, (float)c);
                *(float2*)(s_out + 2 * (t + 1)) = sv;
                r_out[t + 1] = rew;
            }
            cur = nxt;
        }
    }
}

extern "C" void kernel_launch(void* const* d_in, const int* in_sizes, int n_in,
                              void* d_out, int out_size, void* d_ws, size_t ws_size,
                              hipStream_t stream) {
    const float* s0    = (const float*)d_in[0];
    const int*   act   = (const int*)d_in[1];
    const float* world = (const float*)d_in[2];
    float*       out   = (float*)d_out;

    const int B = in_sizes[0] / 2;           // 8192
    const int grid = B / BPB;                // 512 blocks

    rollout_kernel<<<grid, THREADS, 0, stream>>>(s0, act, world, out, B);
}